// Round 2
// baseline (92.379 us; speedup 1.0000x reference)
//
#include <hip/hip_runtime.h>
#include <stdint.h>

#define IN_C 64
#define HH 256
#define WW 256
#define HW (HH * WW)
#define OUT_C 128
#define OH 254
#define OW 254
#define OHW (OH * OW)

#define CPAD 72            // channel stride in shorts: 144 B -> b128 B-frag reads bank-balanced
#define XTROW (WW * CPAD)  // shorts per xt row: 18432 (36864 B), px-major, c fastest
#define XSROW 5120         // shorts per staged LDS row: 10240 B = 10 x 1KB gload chunks (px 0..65 used)

typedef __attribute__((ext_vector_type(4))) float f32x4;
typedef __attribute__((ext_vector_type(8))) __bf16 bf16x8;

__device__ __forceinline__ unsigned short f2bf(float f) {
  union { float f; unsigned u; } v; v.f = f;
  unsigned r = v.u + 0x7FFFu + ((v.u >> 16) & 1u);  // RNE (inputs finite/normal)
  return (unsigned short)(r >> 16);
}

typedef const __attribute__((address_space(1))) unsigned GASU;
typedef __attribute__((address_space(3))) unsigned LASU;
__device__ __forceinline__ void gl_lds16(const void* g, void* l) {
  // 16B per lane, LDS dest = wave-uniform base + lane*16 (hardware rule)
  __builtin_amdgcn_global_load_lds((GASU*)g, (LASU*)l, 16, 0, 0);
}

// One pass over x: fp32 [c][y][x] -> bf16 xt[y][px][cPad72] (the exact LDS tile layout,
// so conv staging is a pure linear global_load_lds copy). Also converts weights into
// A-fragment order (fused, was prep_w):
// wt[tap][ch][mt][lane][j] = bf16( W[o=mt*16+(lane&15)][c=ch*32+(lane>>4)*8+j][tap] )
__global__ __launch_bounds__(256) void prep_x(
    const float* __restrict__ x, const float* __restrict__ w,
    unsigned short* __restrict__ xt, unsigned short* __restrict__ wt) {
  __shared__ __align__(16) unsigned Ls[WW * 36];  // [px][c2] u32 = 2 packed bf16; 36864 B
  const int y = blockIdx.x;
  const int tid = threadIdx.x;
  const int c2 = tid & 31;   // channel pair: channels 2*c2, 2*c2+1
  const int g = tid >> 5;    // 0..7 -> px g*32 .. g*32+31 (1KB contiguous per channel-row)

  const float* b0 = x + (2 * c2) * HW + y * WW + g * 32;
  const float* b1 = b0 + HW;
  f32x4 v0[8], v1[8];
#pragma unroll
  for (int i = 0; i < 8; ++i) v0[i] = *(const f32x4*)(b0 + i * 4);
#pragma unroll
  for (int i = 0; i < 8; ++i) v1[i] = *(const f32x4*)(b1 + i * 4);

  // fused weight prep: 73728 elems over 256 blocks (blocks 0..31 do 2)
  for (int idx = blockIdx.x * 256 + tid; idx < 9 * 8192; idx += 65536) {
    const int j = idx & 7;
    const int ln = (idx >> 3) & 63;
    const int mt = (idx >> 9) & 7;
    const int ch = (idx >> 12) & 1;
    const int tap = idx >> 13;
    const int o = mt * 16 + (ln & 15);
    const int c = ch * 32 + (ln >> 4) * 8 + j;
    wt[idx] = f2bf(w[(o * IN_C + c) * 9 + tap]);
  }

  // transpose via LDS: lanes = c2 (32 banks 1-way, g-halves alias 2-way = free)
#pragma unroll
  for (int i = 0; i < 8; ++i)
#pragma unroll
    for (int j = 0; j < 4; ++j) {
      const int px = g * 32 + i * 4 + j;
      Ls[px * 36 + c2] = (unsigned)f2bf(v0[i][j]) | ((unsigned)f2bf(v1[i][j]) << 16);
    }
  __syncthreads();

  // stream the whole 36864 B row out, coalesced 16B stores
  uint4* dst = (uint4*)(xt + y * XTROW);
  const uint4* src = (const uint4*)Ls;
#pragma unroll
  for (int k = 0; k < 9; ++k) dst[tid + k * 256] = src[tid + k * 256];
}

// 256-thread block: 2 output rows x 64 px x 128 ch. 4 waves = (row 0..1, mhalf 0..1).
// Staging = 4 rows x 10 linear global_load_lds chunks (no VALU, no ds_write, bf16).
__global__ __launch_bounds__(256, 3) void conv_mfma(
    const unsigned short* __restrict__ xt, const unsigned short* __restrict__ wt,
    const float* __restrict__ bias, float* __restrict__ out) {
  __shared__ __align__(16) unsigned short Xs[4 * XSROW];  // 40960 B

  const int tid  = threadIdx.x;
  const int wave = tid >> 6;
  const int lane = tid & 63;
  const int x0 = blockIdx.x * 64;   // 0,64,128,192 (mask stores at xc >= 254)
  const int y0 = blockIdx.y * 2;    // 0..252; staged rows y0..y0+3 all <= 255

  const int mhalf = wave & 1;   // half of the 128 out-channels
  const int row   = wave >> 1;  // which of the 2 output rows
  const int nlane = lane & 15;
  const int quad  = lane >> 4;

  // ---- stage: wave w copies xt row (y0+w), px x0..x0+65 (+pad) -> Xs[w], linear.
  // Chunk 9 reads 736B past the 66-px slice: real neighbouring data except the very
  // last row+tile, which reads workspace slack; those px feed only masked columns
  // (px 64,65 -> xc >= 254; px >= 66 never read by B-frags).
  {
    const char* gsrc = (const char*)(xt + (y0 + wave) * XTROW + x0 * CPAD);
    char* ldst = (char*)&Xs[wave * XSROW];
#pragma unroll
    for (int k = 0; k < 10; ++k)
      gl_lds16(gsrc + k * 1024 + lane * 16, ldst + k * 1024);
  }

  // A-frag base; chunk-0 prefetch — in flight across the staging drain
  const bf16x8* __restrict__ Wp = ((const bf16x8*)wt) + lane + (mhalf * 4) * 64;
  bf16x8 afA[4], afB[4];
#pragma unroll
  for (int mt = 0; mt < 4; ++mt) afA[mt] = Wp[mt * 64];

  // accumulators init with bias (C/D row = quad*4+reg = out-ch)
  f32x4 acc[4][4];
#pragma unroll
  for (int mt = 0; mt < 4; ++mt) {
    const f32x4 bv = *(const f32x4*)(bias + (mhalf * 4 + mt) * 16 + quad * 4);
#pragma unroll
    for (int nt = 0; nt < 4; ++nt) acc[mt][nt] = bv;
  }

  __syncthreads();  // drains gload_lds (vmcnt) — Xs ready; the only barrier

  // ---- 9 taps x 2 ch-chunks; A double-buffered one chunk ahead, all indices static
#pragma unroll 1
  for (int pair = 0; pair < 9; ++pair) {
    const int ky = pair / 3;
    const int kx = pair - ky * 3;
    const int r = row + ky;           // 0..3
    const unsigned short* xrow = &Xs[r * XSROW + kx * CPAD + quad * 8];

    // prefetch odd chunk (tap=pair, ch=1)
#pragma unroll
    for (int mt = 0; mt < 4; ++mt) afB[mt] = Wp[((2 * pair + 1) * 8 + mt) * 64];

    {  // compute even chunk (ch = 0) with afA
      bf16x8 bfr[4];
#pragma unroll
      for (int nt = 0; nt < 4; ++nt)
        bfr[nt] = *(const bf16x8*)&xrow[(nt * 16 + nlane) * CPAD];
#pragma unroll
      for (int mt = 0; mt < 4; ++mt)
#pragma unroll
        for (int nt = 0; nt < 4; ++nt)
          acc[mt][nt] = __builtin_amdgcn_mfma_f32_16x16x32_bf16(afA[mt], bfr[nt], acc[mt][nt], 0, 0, 0);
    }

    if (pair < 8) {  // prefetch next pair's even chunk
#pragma unroll
      for (int mt = 0; mt < 4; ++mt) afA[mt] = Wp[((2 * pair + 2) * 8 + mt) * 64];
    }

    {  // compute odd chunk (ch = 1) with afB
      bf16x8 bfr[4];
#pragma unroll
      for (int nt = 0; nt < 4; ++nt)
        bfr[nt] = *(const bf16x8*)&xrow[(nt * 16 + nlane) * CPAD + 32];
#pragma unroll
      for (int mt = 0; mt < 4; ++mt)
#pragma unroll
        for (int nt = 0; nt < 4; ++nt)
          acc[mt][nt] = __builtin_amdgcn_mfma_f32_16x16x32_bf16(afB[mt], bfr[nt], acc[mt][nt], 0, 0, 0);
    }
  }

  // ---- epilogue: C/D col = lane&15 (pixel), row = quad*4+reg (out-ch); plain stores
  const int y = y0 + row;  // always < 254
#pragma unroll
  for (int mt = 0; mt < 4; ++mt) {
    const int obase = (mhalf * 4 + mt) * 16 + quad * 4;
#pragma unroll
    for (int nt = 0; nt < 4; ++nt) {
      const int xc = x0 + nt * 16 + nlane;
      if (xc < OW) {
        float* dst = out + obase * OHW + y * OW + xc;
#pragma unroll
        for (int reg = 0; reg < 4; ++reg)
          dst[reg * OHW] = acc[mt][nt][reg];
      }
    }
  }
}

extern "C" void kernel_launch(void* const* d_in, const int* in_sizes, int n_in,
                              void* d_out, int out_size, void* d_ws, size_t ws_size,
                              hipStream_t stream) {
  const float* x = (const float*)d_in[0];
  const float* w = (const float*)d_in[1];
  const float* b = (const float*)d_in[2];
  float* out = (float*)d_out;
  unsigned short* wt = (unsigned short*)d_ws;                        // 147456 B A-frag weights
  unsigned short* xtb = (unsigned short*)((char*)d_ws + 262144);     // 9.44 MB bf16 tiled x (+slack)

  prep_x<<<dim3(256), dim3(256), 0, stream>>>(x, w, xtb, wt);
  conv_mfma<<<dim3(4, 127), dim3(256), 0, stream>>>(xtb, wt, b, out);
}

// Round 3
// 89.779 us; speedup vs baseline: 1.0290x; 1.0290x over previous
//
#include <hip/hip_runtime.h>
#include <stdint.h>

#define IN_C 64
#define HH 256
#define WW 256
#define HW (HH * WW)
#define OUT_C 128
#define OH 254
#define OW 254
#define OHW (OH * OW)

#define XR 6     // staged input rows (4 out rows + 2 halo)
#define XW 66    // staged input width (64 + 2 halo)
#define CPAD 72  // channel stride in shorts: 144 B -> b128 B-frag reads bank-balanced

typedef __attribute__((ext_vector_type(4))) float f32x4;
typedef __attribute__((ext_vector_type(8))) __bf16 bf16x8;

__device__ __forceinline__ unsigned short f2bf(float f) {
  union { float f; unsigned u; } v; v.f = f;
  unsigned r = v.u + 0x7FFFu + ((v.u >> 16) & 1u);  // RNE (inputs finite/normal)
  return (unsigned short)(r >> 16);
}

// Weights -> A-fragment order bf16:
// wt[tap][ch][mt][lane][j] = bf16( W[o=mt*16+(lane&15)][c=ch*32+(lane>>4)*8+j][tap] )
// A-frag load is a verbatim per-lane global_load_dwordx4 (L1/L2-resident, no LDS).
__global__ void prep_w(const float* __restrict__ w, unsigned short* __restrict__ wt) {
  const int idx = blockIdx.x * 256 + threadIdx.x;
  if (idx >= 9 * 8192) return;
  const int j    = idx & 7;
  const int lane = (idx >> 3) & 63;
  const int mt   = (idx >> 9) & 7;
  const int ch   = (idx >> 12) & 1;
  const int tap  = idx >> 13;
  const int o = mt * 16 + (lane & 15);
  const int c = ch * 32 + (lane >> 4) * 8 + j;
  wt[idx] = f2bf(w[(o * IN_C + c) * 9 + tap]);
}

// 512-thread block: 4 output rows x 64 px x 128 ch. 8 waves = (row 0..3, mhalf 0..1).
// 6 staged input rows amortize the halo 1.5x; single barrier. Grid 4x64 = 256 blocks
// = 1/CU (lowest-traffic structure measured; occupancy variants were nulls R1/R2).
__global__ __launch_bounds__(512, 2) void conv_mfma(
    const float* __restrict__ x, const unsigned short* __restrict__ wt,
    const float* __restrict__ bias, float* __restrict__ out) {
  __shared__ __align__(16) unsigned short Xs[XR * XW * CPAD];  // 57024 B

  const int tid  = threadIdx.x;
  const int wave = tid >> 6;
  const int lane = tid & 63;
  const int x0 = blockIdx.x * 64;   // 0,64,128,192 (mask stores at xc >= 254)
  const int y0 = blockIdx.y * 4;    // 0..252 (mask stores at y >= 254)

  const int mhalf = wave & 1;   // half of the 128 out-channels
  const int row   = wave >> 1;  // which of the 4 output rows
  const int nlane = lane & 15;
  const int quad  = lane >> 4;

  // A-frag base; chunk-0 prefetch first — in flight across the staging phase
  const bf16x8* __restrict__ Wp = ((const bf16x8*)wt) + lane + (mhalf * 4) * 64;
  bf16x8 afA[4], afB[4];
#pragma unroll
  for (int mt = 0; mt < 4; ++mt) afA[mt] = Wp[mt * 64];

  // ---- stage Xs: Xs[r][xx][c] = bf16(x[c][y0+r][x0+xx])
  // thread = (cq 0..15, xh 0..15, rhalf 0..1). ALL 14 global loads (12 main f32x4 +
  // 2 halo scalars) are issued before any convert/ds_write: at 1 block/CU the stage
  // phase is a serial latency chain — hoisting removes dependent-load round-trips.
  {
    const int cq = tid & 15;          // channels cq*4 .. cq*4+3
    const int xh = (tid >> 4) & 15;   // xx = xh*4 .. xh*4+3
    const int r3 = (tid >> 8) * 3;    // rows r3 .. r3+2

    // main loads: 3 rows x 4 channels, 16B each (4 xh-lanes tile each 64B line)
    f32x4 vv[3][4];
#pragma unroll
    for (int k = 0; k < 3; ++k) {
      const int r = r3 + k;
      const int yr = (y0 + r > 255) ? 255 : (y0 + r);  // clamp: only feeds masked rows
      const float* bx = x + yr * WW + x0 + xh * 4;
#pragma unroll
      for (int cc = 0; cc < 4; ++cc)
        vv[k][cc] = *(const f32x4*)(bx + (cq * 4 + cc) * HW);
    }

    // halo loads xx = 64,65 : 6 rows x 2 px x 64 ch (clamped; feeds masked cols only)
    float hv0, hv1 = 0.f;
    int a0, a1 = 0;
    {
      const int c = tid & 63, q = tid >> 6;       // q 0..7
      const int xxt = 64 + (q & 1), r = q >> 1;   // r 0..3
      const int yr = (y0 + r > 255) ? 255 : (y0 + r);
      int xg = x0 + xxt; if (xg > WW - 1) xg = WW - 1;
      hv0 = x[c * HW + yr * WW + xg];
      a0 = (r * XW + xxt) * CPAD + c;
    }
    const bool has2 = tid < 256;
    if (has2) {
      const int k = tid + 512;
      const int c = k & 63, q = k >> 6;           // q 8..11
      const int xxt = 64 + (q & 1), r = q >> 1;   // r 4..5
      const int yr = (y0 + r > 255) ? 255 : (y0 + r);
      int xg = x0 + xxt; if (xg > WW - 1) xg = WW - 1;
      hv1 = x[c * HW + yr * WW + xg];
      a1 = (r * XW + xxt) * CPAD + c;
    }

    // converts + packed ds_write_b64 (4 ch per write): 16 lanes of one xh-group
    // cover all 32 banks; xh-groups alias 2-way = free.
#pragma unroll
    for (int k = 0; k < 3; ++k) {
      const int r = r3 + k;
#pragma unroll
      for (int xxi = 0; xxi < 4; ++xxi) {
        unsigned u0 = (unsigned)f2bf(vv[k][0][xxi]) | ((unsigned)f2bf(vv[k][1][xxi]) << 16);
        unsigned u1 = (unsigned)f2bf(vv[k][2][xxi]) | ((unsigned)f2bf(vv[k][3][xxi]) << 16);
        *(uint2*)&Xs[(r * XW + xh * 4 + xxi) * CPAD + cq * 4] = make_uint2(u0, u1);
      }
    }
    Xs[a0] = f2bf(hv0);
    if (has2) Xs[a1] = f2bf(hv1);
  }

  // accumulators init with bias (C/D row = quad*4+reg = out-ch)
  f32x4 acc[4][4];
#pragma unroll
  for (int mt = 0; mt < 4; ++mt) {
    const f32x4 bv = *(const f32x4*)(bias + (mhalf * 4 + mt) * 16 + quad * 4);
#pragma unroll
    for (int nt = 0; nt < 4; ++nt) acc[mt][nt] = bv;
  }

  __syncthreads();  // Xs ready — the only barrier in the kernel

  // ---- 9 taps x 2 ch-chunks; A double-buffered one chunk ahead, all indices static
#pragma unroll 1
  for (int pair = 0; pair < 9; ++pair) {
    const int ky = pair / 3;
    const int kx = pair - ky * 3;
    const int r = row + ky;
    const unsigned short* xrow = &Xs[(r * XW + kx) * CPAD + quad * 8];

    // prefetch odd chunk (tap=pair, ch=1)
#pragma unroll
    for (int mt = 0; mt < 4; ++mt) afB[mt] = Wp[((2 * pair + 1) * 8 + mt) * 64];

    {  // compute even chunk (ch = 0) with afA
      bf16x8 bfr[4];
#pragma unroll
      for (int nt = 0; nt < 4; ++nt)
        bfr[nt] = *(const bf16x8*)&xrow[(nt * 16 + nlane) * CPAD];
#pragma unroll
      for (int mt = 0; mt < 4; ++mt)
#pragma unroll
        for (int nt = 0; nt < 4; ++nt)
          acc[mt][nt] = __builtin_amdgcn_mfma_f32_16x16x32_bf16(afA[mt], bfr[nt], acc[mt][nt], 0, 0, 0);
    }

    if (pair < 8) {  // prefetch next pair's even chunk
#pragma unroll
      for (int mt = 0; mt < 4; ++mt) afA[mt] = Wp[((2 * pair + 2) * 8 + mt) * 64];
    }

    {  // compute odd chunk (ch = 1) with afB
      bf16x8 bfr[4];
#pragma unroll
      for (int nt = 0; nt < 4; ++nt)
        bfr[nt] = *(const bf16x8*)&xrow[(nt * 16 + nlane) * CPAD + 32];
#pragma unroll
      for (int mt = 0; mt < 4; ++mt)
#pragma unroll
        for (int nt = 0; nt < 4; ++nt)
          acc[mt][nt] = __builtin_amdgcn_mfma_f32_16x16x32_bf16(afB[mt], bfr[nt], acc[mt][nt], 0, 0, 0);
    }
  }

  // ---- epilogue: C/D col = lane&15 (pixel), row = quad*4+reg (out-ch); plain stores
  const int y = y0 + row;
  if (y < OH) {
#pragma unroll
    for (int mt = 0; mt < 4; ++mt) {
      const int obase = (mhalf * 4 + mt) * 16 + quad * 4;
#pragma unroll
      for (int nt = 0; nt < 4; ++nt) {
        const int xc = x0 + nt * 16 + nlane;
        if (xc < OW) {
          float* dst = out + obase * OHW + y * OW + xc;
#pragma unroll
          for (int reg = 0; reg < 4; ++reg)
            dst[reg * OHW] = acc[mt][nt][reg];
        }
      }
    }
  }
}

extern "C" void kernel_launch(void* const* d_in, const int* in_sizes, int n_in,
                              void* d_out, int out_size, void* d_ws, size_t ws_size,
                              hipStream_t stream) {
  const float* x = (const float*)d_in[0];
  const float* w = (const float*)d_in[1];
  const float* b = (const float*)d_in[2];
  float* out = (float*)d_out;
  unsigned short* wt = (unsigned short*)d_ws;  // 147456 B fragment-ordered bf16 weights

  prep_w<<<dim3(288), dim3(256), 0, stream>>>(w, wt);
  conv_mfma<<<dim3(4, 64), dim3(512), 0, stream>>>(x, wt, b, out);
}